// Round 11
// baseline (460.401 us; speedup 1.0000x reference)
//
#include <hip/hip_runtime.h>
#include <hip/hip_bf16.h>
#include <cstddef>

#define D_MODEL 1024
#define D_STATE 16
#define D_CONV 4
#define DT_RANK 64
#define D_INNER 2048
#define BB 2
#define LL 2048
#define TT (BB * LL)          // 4096 tokens
#define NSEG 64
#define SEGLEN (LL / NSEG)    // 32
#define NCHAN (BB * D_INNER)  // 4096

typedef __bf16 bf16x8 __attribute__((ext_vector_type(8)));
typedef float floatx4 __attribute__((ext_vector_type(4)));
typedef unsigned short ushortx8 __attribute__((ext_vector_type(8)));

__device__ __forceinline__ unsigned short f2bf(float f) {
  unsigned u = __float_as_uint(f);
  unsigned r = u + 0x7FFF + ((u >> 16) & 1);  // round-to-nearest-even
  return (unsigned short)(r >> 16);
}
__device__ __forceinline__ float b2f(unsigned short v) {
  return __uint_as_float((unsigned)v << 16);
}

// ---------------------------------------------------------------------------
// prep: blocks [0,TT) = LayerNorm; rest = weight casts + zero xd + zero out.
// f4 ranges: in_proj [0,1048576) out_proj [.,1572864) x_proj [.,1622016)
// dt_proj [.,1654784) zero-xd [.,1753088) zero-out [.,2801664)
// ---------------------------------------------------------------------------
__global__ __launch_bounds__(256) void prep_kernel(
    const float* __restrict__ x, const float* __restrict__ lnw,
    const float* __restrict__ lnb, unsigned short* __restrict__ xnb,
    const float* __restrict__ w0, const float* __restrict__ w1,
    const float* __restrict__ w2, const float* __restrict__ w3,
    unsigned short* __restrict__ wdst, float* __restrict__ xd,
    float* __restrict__ outz) {
  const int tid = threadIdx.x;
  if (blockIdx.x < TT) {
    int t = blockIdx.x;
    const float4* xr = reinterpret_cast<const float4*>(x + (size_t)t * D_MODEL);
    float4 xv = xr[tid];
    float s = xv.x + xv.y + xv.z + xv.w;
    float sq = xv.x * xv.x + xv.y * xv.y + xv.z * xv.z + xv.w * xv.w;
    for (int off = 32; off >= 1; off >>= 1) {
      s += __shfl_down(s, off);
      sq += __shfl_down(sq, off);
    }
    __shared__ float red[8];
    int wave = tid >> 6;
    if ((tid & 63) == 0) { red[wave * 2] = s; red[wave * 2 + 1] = sq; }
    __syncthreads();
    if (tid == 0) {
      float S = 0.f, Q = 0.f;
      for (int i = 0; i < 4; ++i) { S += red[2 * i]; Q += red[2 * i + 1]; }
      float mean = S * (1.f / D_MODEL);
      float var = Q * (1.f / D_MODEL) - mean * mean;
      red[0] = mean;
      red[1] = rsqrtf(var + 1e-5f);
    }
    __syncthreads();
    float mean = red[0], inv = red[1];
    float4 wv = reinterpret_cast<const float4*>(lnw)[tid];
    float4 bv = reinterpret_cast<const float4*>(lnb)[tid];
    ushort4 o;
    o.x = f2bf((xv.x - mean) * inv * wv.x + bv.x);
    o.y = f2bf((xv.y - mean) * inv * wv.y + bv.y);
    o.z = f2bf((xv.z - mean) * inv * wv.z + bv.z);
    o.w = f2bf((xv.w - mean) * inv * wv.w + bv.w);
    reinterpret_cast<ushort4*>(xnb + (size_t)t * D_MODEL)[tid] = o;
    return;
  }
  int i = (blockIdx.x - TT) * 256 + tid;
  const float* src;
  int off;
  if (i < 1048576) { src = w0; off = 0; }
  else if (i < 1572864) { src = w1; off = 1048576; }
  else if (i < 1622016) { src = w2; off = 1572864; }
  else if (i < 1654784) { src = w3; off = 1622016; }
  else if (i < 1753088) {
    float4 zz = {0.f, 0.f, 0.f, 0.f};
    reinterpret_cast<float4*>(xd)[i - 1654784] = zz;
    return;
  } else {
    float4 zz = {0.f, 0.f, 0.f, 0.f};
    reinterpret_cast<float4*>(outz)[i - 1753088] = zz;
    return;
  }
  float4 v = reinterpret_cast<const float4*>(src)[i - off];
  ushort4 o;
  o.x = f2bf(v.x); o.y = f2bf(v.y); o.z = f2bf(v.z); o.w = f2bf(v.w);
  reinterpret_cast<ushort4*>(wdst)[i] = o;
}

// ---------------------------------------------------------------------------
// bf16 MFMA NT GEMM. BM=128, BN=WNF*32, BK=64, LDS <= 32 KB.
// CLAMP: clamp B rows to N-1 (only x_proj needs it).
// EPI 0: f32 (atomic if kslice>1); 2: v+resid f32 (atomic if kslice>1,
//        resid folded into kz==0 partial, C pre-zeroed); 4: in_proj dual bf16.
// ---------------------------------------------------------------------------
template <int WNF, int EPI, bool CLAMP, typename OT>
__global__ __launch_bounds__(256) void gemm_bf16_kernel(
    const unsigned short* __restrict__ A, int lda,
    const unsigned short* __restrict__ B, int ldb,
    OT* __restrict__ C, int ldc, int M, int N, int K,
    const float* __restrict__ bias, const float* __restrict__ resid, int ldr,
    unsigned short* __restrict__ C2, int kslice) {
  constexpr int BN = WNF * 32;
  constexpr int BSLOTS = BN * 8;
  constexpr int SMEM_USH = 8192 + BN * 64;
  __shared__ unsigned short sm[SMEM_USH];
  unsigned short* Atile = sm;
  unsigned short* Btile = sm + 8192;

  const int tid = threadIdx.x;
  const int lane = tid & 63;
  const int wv = tid >> 6;
  const int wrow = (wv >> 1) * 64;
  const int wcol = (wv & 1) * (WNF * 16);
  int gx = gridDim.x, gy = gridDim.y;
  int lid = blockIdx.y * gx + blockIdx.x;
  int rpx = gy >> 3;
  int xcd = lid & 7;
  int qq0 = lid >> 3;
  int by = xcd * rpx + (qq0 % rpx);
  int bx = qq0 / rpx;
  const int row0 = by * 128;
  const int col0 = bx * BN;
  const int m = lane & 15;
  const int q = lane >> 4;

  int k0lo = 0, k0hi = K;
  if (kslice > 1) {
    int ks = K / kslice;
    k0lo = blockIdx.z * ks;
    k0hi = k0lo + ks;
  }

  floatx4 acc[4][WNF] = {};

  for (int k0 = k0lo; k0 < k0hi; k0 += 64) {
#pragma unroll
    for (int t = 0; t < 4; ++t) {
      int slot = wv * 256 + t * 64 + lane;
      int row = slot >> 3;
      int kg = (slot & 7) ^ (row & 7);
      const unsigned short* ga = A + (size_t)(row0 + row) * lda + k0 + kg * 8;
      __builtin_amdgcn_global_load_lds(
          (const __attribute__((address_space(1))) void*)ga,
          (__attribute__((address_space(3))) void*)(Atile + slot * 8), 16, 0, 0);
    }
#pragma unroll
    for (int t = 0; t < BSLOTS / 256; ++t) {
      int slot = t * 256 + tid;
      int row = slot >> 3;
      int kg = (slot & 7) ^ (row & 7);
      int rowB = col0 + row;
      if (CLAMP && rowB >= N) rowB = N - 1;
      const unsigned short* gb = B + (size_t)rowB * ldb + k0 + kg * 8;
      __builtin_amdgcn_global_load_lds(
          (const __attribute__((address_space(1))) void*)gb,
          (__attribute__((address_space(3))) void*)(Btile + slot * 8), 16, 0, 0);
    }
    __syncthreads();
#pragma unroll
    for (int s = 0; s < 2; ++s) {
      int xr = ((s * 4 + q) ^ (m & 7)) * 8;
      bf16x8 af[4], bfr[WNF];
#pragma unroll
      for (int i = 0; i < 4; ++i)
        af[i] = *reinterpret_cast<const bf16x8*>(
            Atile + (wrow + i * 16 + m) * 64 + xr);
#pragma unroll
      for (int j = 0; j < WNF; ++j)
        bfr[j] = *reinterpret_cast<const bf16x8*>(
            Btile + (wcol + j * 16 + m) * 64 + xr);
#pragma unroll
      for (int i = 0; i < 4; ++i)
#pragma unroll
        for (int j = 0; j < WNF; ++j)
          acc[i][j] = __builtin_amdgcn_mfma_f32_16x16x32_bf16(
              af[i], bfr[j], acc[i][j], 0, 0, 0);
    }
    __syncthreads();
  }

  if (EPI == 4) {
    const bool zhalf = (col0 >= D_INNER);
    unsigned short* Cb;
    int cb;
    if (zhalf) { Cb = C2; cb = col0 - D_INNER + wcol; }
    else { Cb = (unsigned short*)C; cb = col0 + wcol; }
    constexpr int LPR = WNF * 2;
    constexpr int RPI = 64 / LPR;
#pragma unroll
    for (int round = 0; round < 2; ++round) {
      unsigned short* st = sm + wv * 2112;
      __syncthreads();
#pragma unroll
      for (int ii = 0; ii < 2; ++ii) {
        int i = round * 2 + ii;
#pragma unroll
        for (int j = 0; j < WNF; ++j)
#pragma unroll
          for (int r = 0; r < 4; ++r) {
            float v = acc[i][j][r];
            if (zhalf) v = v / (1.f + expf(-v));
            st[(ii * 16 + q * 4 + r) * 66 + j * 16 + m] = f2bf(v);
          }
      }
      __syncthreads();
#pragma unroll
      for (int t = 0; t < 32 / RPI; ++t) {
        int r = t * RPI + lane / LPR;
        int co = (lane % LPR) * 8;
        ushortx8 val = *reinterpret_cast<const ushortx8*>(st + r * 66 + co);
        *reinterpret_cast<ushortx8*>(
            Cb + (size_t)(row0 + wrow + round * 32 + r) * ldc + cb + co) = val;
      }
    }
  } else {
#pragma unroll
    for (int j = 0; j < WNF; ++j) {
      int gc = col0 + wcol + j * 16 + m;
      if (CLAMP && gc >= N) continue;
#pragma unroll
      for (int i = 0; i < 4; ++i) {
#pragma unroll
        for (int r = 0; r < 4; ++r) {
          int gr = row0 + wrow + i * 16 + q * 4 + r;
          float v = acc[i][j][r];
          if (EPI == 2) {
            if (kslice > 1) {
              if (blockIdx.z == 0) v += resid[(size_t)gr * ldr + gc];
              atomicAdd(&((float*)C)[(size_t)gr * ldc + gc], v);
            } else {
              ((float*)C)[(size_t)gr * ldc + gc] = v + resid[(size_t)gr * ldr + gc];
            }
          } else {
            if (kslice > 1)
              atomicAdd(&((float*)C)[(size_t)gr * ldc + gc], v);
            else
              ((float*)C)[(size_t)gr * ldc + gc] = v;
          }
        }
      }
    }
  }
}

// ---------------------------------------------------------------------------
// dtscan: dt_proj GEMM (K=64, one BK iteration) + softplus -> delta bf16
// (global, for scan_final) + partial scan phase, all in one kernel.
// ---------------------------------------------------------------------------
__global__ __launch_bounds__(256) void dtscan_kernel(
    const float* __restrict__ xd, const unsigned short* __restrict__ wdt,
    const float* __restrict__ dtb, const unsigned short* __restrict__ ucb,
    const float* __restrict__ A_log, unsigned short* __restrict__ deltab,
    float* __restrict__ aprod_buf, float* __restrict__ hend_buf) {
  __shared__ unsigned short sm[20736];  // 41472 B
  unsigned short* Atile = sm;
  unsigned short* Btile = sm + 8192;

  const int tid = threadIdx.x;
  const int lane = tid & 63;
  const int wv = tid >> 6;
  const int wrow = (wv >> 1) * 64;
  const int wcol = (wv & 1) * 64;
  int gx = gridDim.x, gy = gridDim.y;
  int lid = blockIdx.y * gx + blockIdx.x;
  int rpx = gy >> 3;
  int xcd = lid & 7;
  int qq0 = lid >> 3;
  int by = xcd * rpx + (qq0 % rpx);
  int bx = qq0 / rpx;
  const int row0 = by * 128;
  const int col0 = bx * 128;
  const int m = lane & 15;
  const int q = lane >> 4;

  // --- GEMM: A = xd (f32, lda=96, K=64) staged+converted; B = wdt ---
#pragma unroll
  for (int t = 0; t < 4; ++t) {
    int slot = wv * 256 + t * 64 + lane;
    int row = slot >> 3;
    int kg = (slot & 7) ^ (row & 7);
    const float* ga = xd + (size_t)(row0 + row) * 96 + kg * 8;
    float4 v0 = *reinterpret_cast<const float4*>(ga);
    float4 v1 = *reinterpret_cast<const float4*>(ga + 4);
    ushortx8 pk;
    pk[0] = f2bf(v0.x); pk[1] = f2bf(v0.y); pk[2] = f2bf(v0.z); pk[3] = f2bf(v0.w);
    pk[4] = f2bf(v1.x); pk[5] = f2bf(v1.y); pk[6] = f2bf(v1.z); pk[7] = f2bf(v1.w);
    *reinterpret_cast<ushortx8*>(Atile + slot * 8) = pk;
  }
#pragma unroll
  for (int t = 0; t < 4; ++t) {
    int slot = t * 256 + tid;
    int row = slot >> 3;
    int kg = (slot & 7) ^ (row & 7);
    const unsigned short* gb = wdt + (size_t)(col0 + row) * DT_RANK + kg * 8;
    __builtin_amdgcn_global_load_lds(
        (const __attribute__((address_space(1))) void*)gb,
        (__attribute__((address_space(3))) void*)(Btile + slot * 8), 16, 0, 0);
  }
  __syncthreads();
  floatx4 acc[4][4] = {};
#pragma unroll
  for (int s = 0; s < 2; ++s) {
    int xr = ((s * 4 + q) ^ (m & 7)) * 8;
    bf16x8 af[4], bfr[4];
#pragma unroll
    for (int i = 0; i < 4; ++i)
      af[i] = *reinterpret_cast<const bf16x8*>(Atile + (wrow + i * 16 + m) * 64 + xr);
#pragma unroll
    for (int j = 0; j < 4; ++j)
      bfr[j] = *reinterpret_cast<const bf16x8*>(Btile + (wcol + j * 16 + m) * 64 + xr);
#pragma unroll
    for (int i = 0; i < 4; ++i)
#pragma unroll
      for (int j = 0; j < 4; ++j)
        acc[i][j] = __builtin_amdgcn_mfma_f32_16x16x32_bf16(
            af[i], bfr[j], acc[i][j], 0, 0, 0);
  }
  __syncthreads();  // all LDS reads done; overlay st/Bf

  // --- softplus(acc + bias) -> st[128][130] (bf16) ---
  unsigned short* st = sm;                 // 128*130 ush = 16640
  float* Bf = (float*)(sm + 16640);        // 128*16 f32 = 8192 B
  float bj[4];
#pragma unroll
  for (int j = 0; j < 4; ++j) bj[j] = dtb[col0 + wcol + j * 16 + m];
#pragma unroll
  for (int i = 0; i < 4; ++i)
#pragma unroll
    for (int j = 0; j < 4; ++j)
#pragma unroll
      for (int r = 0; r < 4; ++r) {
        float xv = acc[i][j][r] + bj[j];
        float sp = fmaxf(xv, 0.f) + log1pf(expf(-fabsf(xv)));
        int lrow = wrow + i * 16 + q * 4 + r;
        int lcol = wcol + j * 16 + m;
        st[lrow * 130 + lcol] = f2bf(sp);
      }
  // --- stage B-values (xd cols 64..79) for the scan phase ---
#pragma unroll
  for (int e = 0; e < 2; ++e) {
    int f4 = e * 256 + tid;  // 512 float4 total
    int row = f4 >> 2, part = f4 & 3;
    float4 v = *reinterpret_cast<const float4*>(
        xd + (size_t)(row0 + row) * 96 + 64 + part * 4);
    *reinterpret_cast<float4*>(Bf + row * 16 + part * 4) = v;
  }
  __syncthreads();

  // --- global delta store (coalesced 16B) ---
#pragma unroll
  for (int e = 0; e < 8; ++e) {
    int c = e * 256 + tid;  // 2048 chunks
    int rrow = c >> 4, co = (c & 15) * 8;
    ushortx8 val = *reinterpret_cast<const ushortx8*>(st + rrow * 130 + co);
    *reinterpret_cast<ushortx8*>(
        deltab + (size_t)(row0 + rrow) * D_INNER + col0 + co) = val;
  }

  // --- partial scan phase ---
  const int ch = tid & 127;
  const int sp = tid >> 7;
  const int d = col0 + ch;
  const int b = row0 >> 11;
  const int chan = b * D_INNER + d;
  floatx4 Ac[4];
  {
    const floatx4* ar = reinterpret_cast<const floatx4*>(A_log + (size_t)d * D_STATE);
#pragma unroll
    for (int k = 0; k < 4; ++k) {
      floatx4 v = ar[k];
      for (int j = 0; j < 4; ++j) Ac[k][j] = -__expf(v[j]) * 1.4426950408889634f;
    }
  }
#pragma unroll
  for (int ss = 0; ss < 2; ++ss) {
    int lbase = sp * 64 + ss * 32;
    int seg = ((row0 & (LL - 1)) >> 5) + sp * 2 + ss;
    floatx4 h[4] = {};
    float S = 0.f;
    for (int l = 0; l < SEGLEN; ++l) {
      int lr = lbase + l;
      float dl = b2f(st[lr * 130 + ch]);
      float ul = b2f(ucb[(size_t)(row0 + lr) * D_INNER + d]);
      float dlul = dl * ul;
      S += dl;
#pragma unroll
      for (int k = 0; k < 4; ++k) {
        floatx4 bv = *reinterpret_cast<const floatx4*>(Bf + lr * 16 + k * 4);
        floatx4 a;
        for (int j = 0; j < 4; ++j) a[j] = __builtin_amdgcn_exp2f(dl * Ac[k][j]);
        h[k] = a * h[k] + dlul * bv;
      }
    }
    size_t base = ((size_t)seg * NCHAN + chan) * D_STATE;
#pragma unroll
    for (int k = 0; k < 4; ++k) {
      floatx4 ap;
      for (int j = 0; j < 4; ++j) ap[j] = __builtin_amdgcn_exp2f(S * Ac[k][j]);
      *reinterpret_cast<floatx4*>(hend_buf + base + k * 4) = h[k];
      *reinterpret_cast<floatx4*>(aprod_buf + base + k * 4) = ap;
    }
  }
}

// ---------------------------------------------------------------------------
// Depthwise causal conv (width 4) + SiLU; bf16 in/out, 8 channels per thread.
// ---------------------------------------------------------------------------
__global__ __launch_bounds__(256) void conv_silu_kernel(
    const unsigned short* __restrict__ ub, const float* __restrict__ cw,
    const float* __restrict__ cb, unsigned short* __restrict__ ucb) {
  size_t i8 = ((size_t)blockIdx.x * 256 + threadIdx.x) * 8;
  if (i8 >= (size_t)TT * D_INNER) return;
  int d0 = (int)(i8 & (D_INNER - 1));
  int t = (int)(i8 >> 11);
  int l = t & (LL - 1);
  ushortx8 rows[D_CONV];
#pragma unroll
  for (int k = 0; k < D_CONV; ++k) {
    int ll = l - (D_CONV - 1) + k;
    if (ll >= 0)
      rows[k] = *reinterpret_cast<const ushortx8*>(
          ub + i8 - (size_t)(D_CONV - 1 - k) * D_INNER);
    else
      rows[k] = ushortx8{0, 0, 0, 0, 0, 0, 0, 0};
  }
  ushortx8 o;
#pragma unroll
  for (int j = 0; j < 8; ++j) {
    int d = d0 + j;
    float acc = cb[d];
#pragma unroll
    for (int k = 0; k < D_CONV; ++k)
      acc += b2f(rows[k][j]) * cw[d * D_CONV + k];
    o[j] = f2bf(acc / (1.f + expf(-acc)));
  }
  *reinterpret_cast<ushortx8*>(ucb + i8) = o;
}

// ---------------------------------------------------------------------------
// combine: serial prefix over segments per (chan, n).
// ---------------------------------------------------------------------------
__global__ __launch_bounds__(256) void scan_combine_kernel(
    float* __restrict__ aprod_buf, const float* __restrict__ hend_buf) {
  int idx = blockIdx.x * 256 + threadIdx.x;
  float H = 0.f;
  for (int s = 0; s < NSEG; ++s) {
    size_t si = (size_t)s * (NCHAN * D_STATE) + idx;
    float a = aprod_buf[si];
    float he = hend_buf[si];
    aprod_buf[si] = H;
    H = he + a * H;
  }
}

__global__ __launch_bounds__(256) void scan_final_kernel(
    const unsigned short* __restrict__ deltab, const unsigned short* __restrict__ ucb,
    const float* __restrict__ xd, const unsigned short* __restrict__ zsb,
    const float* __restrict__ A_log, const float* __restrict__ Dv,
    const float* __restrict__ hstart_buf, unsigned short* __restrict__ yb) {
  __shared__ float BCs[SEGLEN][32];
  const int tid = threadIdx.x;
  const int d = blockIdx.x * 256 + tid;
  const int s = blockIdx.y;
  const int b = blockIdx.z;
  const int chan = b * D_INNER + d;
  const size_t tbase = (size_t)b * LL + (size_t)s * SEGLEN;

  {
    int row = tid >> 3, quad = tid & 7;
    *reinterpret_cast<float4*>(&BCs[row][quad * 4]) =
        *reinterpret_cast<const float4*>(xd + (tbase + row) * 96 + 64 + quad * 4);
  }
  floatx4 Ac[4];
  {
    const floatx4* ar = reinterpret_cast<const floatx4*>(A_log + (size_t)d * D_STATE);
#pragma unroll
    for (int k = 0; k < 4; ++k) {
      floatx4 v = ar[k];
      for (int j = 0; j < 4; ++j) Ac[k][j] = -__expf(v[j]) * 1.4426950408889634f;
    }
  }
  float Dd = Dv[d];
  floatx4 h[4];
  {
    size_t base = ((size_t)s * NCHAN + chan) * D_STATE;
#pragma unroll
    for (int k = 0; k < 4; ++k)
      h[k] = *reinterpret_cast<const floatx4*>(hstart_buf + base + k * 4);
  }
  __syncthreads();

  for (int l = 0; l < SEGLEN; ++l) {
    size_t t = tbase + l;
    float dl = b2f(deltab[t * D_INNER + d]);
    float ul = b2f(ucb[t * D_INNER + d]);
    float dlul = dl * ul;
    floatx4 psum = {};
#pragma unroll
    for (int k = 0; k < 4; ++k) {
      floatx4 bv = *reinterpret_cast<const floatx4*>(&BCs[l][k * 4]);
      floatx4 cv = *reinterpret_cast<const floatx4*>(&BCs[l][16 + k * 4]);
      floatx4 a;
      for (int j = 0; j < 4; ++j) a[j] = __builtin_amdgcn_exp2f(dl * Ac[k][j]);
      h[k] = a * h[k] + dlul * bv;
      psum += h[k] * cv;
    }
    float p = psum[0] + psum[1] + psum[2] + psum[3];
    float zs = b2f(zsb[t * D_INNER + d]);
    yb[t * D_INNER + d] = f2bf((p + ul * Dd) * zs);  // in-place over ucb: safe
  }
}

// ---------------------------------------------------------------------------
extern "C" void kernel_launch(void* const* d_in, const int* in_sizes, int n_in,
                              void* d_out, int out_size, void* d_ws, size_t ws_size,
                              hipStream_t stream) {
  const float* x         = (const float*)d_in[0];
  const float* ln_w      = (const float*)d_in[1];
  const float* ln_b      = (const float*)d_in[2];
  const float* in_proj_w = (const float*)d_in[3];
  const float* conv_w    = (const float*)d_in[4];
  const float* conv_b    = (const float*)d_in[5];
  const float* x_proj_w  = (const float*)d_in[6];
  const float* dt_proj_w = (const float*)d_in[7];
  const float* dt_proj_b = (const float*)d_in[8];
  const float* A_log     = (const float*)d_in[9];
  const float* Dvec      = (const float*)d_in[10];
  const float* out_proj_w= (const float*)d_in[11];
  float* out = (float*)d_out;

  unsigned short* wip = (unsigned short*)d_ws;            // 4194304
  unsigned short* wop = wip + 4194304;                    // 2097152
  unsigned short* wxp = wop + 2097152;                    // 196608
  unsigned short* wdt = wxp + 196608;                     // 131072
  unsigned short* xnb = wdt + 131072;                     // T*1024
  unsigned short* ub  = xnb + (size_t)TT * D_MODEL;       // T*2048 (u bf16)
  unsigned short* ucb = ub + (size_t)TT * D_INNER;        // T*2048 (conv out -> y)
  unsigned short* zsb = ucb + (size_t)TT * D_INNER;       // T*2048 (silu(z))
  unsigned short* deltab = zsb + (size_t)TT * D_INNER;    // T*2048 (delta bf16)
  float* xd    = (float*)(deltab + (size_t)TT * D_INNER); // T*96 f32
  float* hend  = xd + (size_t)TT * 96;                    // NSEG*NCHAN*16
  float* aprod = hend + (size_t)NSEG * NCHAN * D_STATE;   // NSEG*NCHAN*16

  // 0. LayerNorm + weight casts + zero xd + zero out
  prep_kernel<<<TT + 10944, 256, 0, stream>>>(x, ln_w, ln_b, xnb, in_proj_w,
                                              out_proj_w, x_proj_w, dt_proj_w,
                                              wip, xd, out);

  // 1. fused in_proj -> u bf16, silu(z) bf16
  gemm_bf16_kernel<4, 4, false, unsigned short><<<dim3(32, 32), 256, 0, stream>>>(
      xnb, D_MODEL, wip, D_MODEL, ub, D_INNER, TT, 2 * D_INNER, D_MODEL,
      nullptr, nullptr, 0, zsb, 1);

  // 2. causal depthwise conv + SiLU -> bf16
  conv_silu_kernel<<<(TT * D_INNER) / (256 * 8), 256, 0, stream>>>(
      ub, conv_w, conv_b, ucb);

  // 3. x_proj -> xd f32 (N=96), BN=64, split-K=4 with atomics
  gemm_bf16_kernel<2, 0, true, float><<<dim3(2, 32, 4), 256, 0, stream>>>(
      ucb, D_INNER, wxp, D_INNER, xd, 96, TT, 96, D_INNER,
      nullptr, nullptr, 0, nullptr, 4);

  // 4. dt_proj + softplus + partial scan, one kernel
  dtscan_kernel<<<dim3(16, 32), 256, 0, stream>>>(
      xd, wdt, dt_proj_b, ucb, A_log, deltab, aprod, hend);

  // 5. combine + final
  scan_combine_kernel<<<(NCHAN * D_STATE) / 256, 256, 0, stream>>>(aprod, hend);
  scan_final_kernel<<<dim3(D_INNER / 256, NSEG, BB), 256, 0, stream>>>(
      deltab, ucb, xd, zsb, A_log, Dvec, aprod, ucb);

  // 6. out_proj + residual, split-K=2 (out pre-zeroed in prep)
  gemm_bf16_kernel<2, 2, false, float><<<dim3(16, 32, 2), 256, 0, stream>>>(
      ucb, D_INNER, wop, D_INNER, out, D_MODEL, TT, D_MODEL, D_INNER,
      nullptr, x, D_MODEL, nullptr, 2);
}